// Round 10
// baseline (207.073 us; speedup 1.0000x reference)
//
#include <hip/hip_runtime.h>

#define B_ 4
#define S_ 2048
#define N_ 2048
#define H_ 16
#define D_ 1024

typedef short s4v __attribute__((ext_vector_type(4)));
typedef short s8v __attribute__((ext_vector_type(8)));
typedef float f4v __attribute__((ext_vector_type(4)));
typedef float f2v __attribute__((ext_vector_type(2)));

__device__ __forceinline__ float bf2f(short s) {
  unsigned u = ((unsigned)(unsigned short)s) << 16;
  float f; __builtin_memcpy(&f, &u, 4); return f;
}
__device__ __forceinline__ short f2bf(float f) {
  unsigned u; __builtin_memcpy(&u, &f, 4);
  u += 0x7fffu + ((u >> 16) & 1u);
  return (short)(u >> 16);
}
__device__ __forceinline__ unsigned pack2bf(float a, float b) {
  unsigned ua, ub;
  __builtin_memcpy(&ua, &a, 4);
  __builtin_memcpy(&ub, &b, 4);
  return __builtin_amdgcn_perm(ub + 0x8000u, ua + 0x8000u, 0x07060302u);
}
// truncating pack (P values; bias cancels in softmax ratio num/denom)
__device__ __forceinline__ unsigned pk2(float a, float b) {
  unsigned ua, ub;
  __builtin_memcpy(&ua, &a, 4);
  __builtin_memcpy(&ub, &b, 4);
  return __builtin_amdgcn_perm(ub, ua, 0x07060302u);
}
__device__ __forceinline__ s8v load8f32(const float* p) {
  const f4v* q = (const f4v*)p;
  f4v a = q[0], b = q[1];
  union { s8v v; unsigned u[4]; } o;
  o.u[0] = pack2bf(a[0], a[1]); o.u[1] = pack2bf(a[2], a[3]);
  o.u[2] = pack2bf(b[0], b[1]); o.u[3] = pack2bf(b[2], b[3]);
  return o.v;
}
// async global->LDS, 16B per lane. LDS dest = first-active-lane base + lane*16;
// every masked call below keeps active lanes starting at lane 0 of a wave.
__device__ __forceinline__ void gld16(const char* g, char* l) {
  __builtin_amdgcn_global_load_lds(
      (const __attribute__((address_space(1))) unsigned*)g,
      (__attribute__((address_space(3))) unsigned*)l, 16, 0, 0);
}

// ===== prep: K-LN (144-B rows) + V transpose (80-B rows) + W' fold ==========
__global__ __launch_bounds__(256) void prep_kernel(
    const float* __restrict__ xk, const float* __restrict__ knw,
    const float* __restrict__ knb, short* __restrict__ kws,
    const float* __restrict__ xv, short* __restrict__ vtp,
    const float* __restrict__ pw, const float* __restrict__ nw_,
    const float* __restrict__ nb_, short* __restrict__ wpb,
    float* __restrict__ t12) {
  __shared__ __align__(16) short vstage[4][2048];
  int blk = blockIdx.x;
  if (blk < 2048) {
    int gid = blk * 256 + threadIdx.x;
    int row = gid >> 6, lane = gid & 63;
    float v = xk[(size_t)row * 64 + lane];
    float s = v;
    #pragma unroll
    for (int mm = 1; mm < 64; mm <<= 1) s += __shfl_xor(s, mm, 64);
    float mean = s * 0.015625f;
    float d = v - mean;
    float vs = d * d;
    #pragma unroll
    for (int mm = 1; mm < 64; mm <<= 1) vs += __shfl_xor(vs, mm, 64);
    float rstd = rsqrtf(vs * 0.015625f + 1e-5f);
    kws[(size_t)row * 72 + lane] = f2bf(d * rstd * knw[lane] + knb[lane]);
  } else if (blk < 2112) {
    int wave = threadIdx.x >> 6, lane = threadIdx.x & 63;
    int u = (blk - 2048) * 4 + wave;        // (b,nb) unit, 0..255
    int b = u >> 6, nb = u & 63;
    int r = lane >> 1, dh = lane & 1;       // V row within 32-block, d-half
    const float* src = xv + ((size_t)(b * N_ + nb * 32 + r)) * 64 + dh * 32;
    int qq = (r & 15) >> 2;
    int slot = ((r >> 4) << 2) + (r & 3);
    short* wbase = &vstage[wave][0];
    #pragma unroll
    for (int jj = 0; jj < 32; jj += 4) {
      f4v f = *(const f4v*)(src + jj);
      #pragma unroll
      for (int e = 0; e < 4; e++) {
        int d = dh * 32 + jj + e;
        wbase[d * 32 + qq * 8 + slot] = f2bf(f[e]);
      }
    }
    __syncthreads();
    // padded: unit stride 2560 shorts (5120 B), d-row stride 40 shorts (80 B)
    s8v* dst = (s8v*)(vtp + (size_t)u * 2560 + lane * 40);
    const s8v* sp = (const s8v*)(wbase + lane * 32);
    dst[0] = sp[0]; dst[1] = sp[1]; dst[2] = sp[2]; dst[3] = sp[3];
  } else {
    // W' builder: W'_jk = bf16(nw_k*W_jk); t1_j = sum nw_k W_jk; t2_j = sum nb_k W_jk
    int jr = threadIdx.x >> 4;
    int lc = (threadIdx.x & 15) * 64;
    int j = (blk - 2112) * 16 + jr;
    const float* wr = pw + (size_t)j * 1024 + lc;
    float t1p = 0.f, t2p = 0.f;
    #pragma unroll
    for (int c = 0; c < 64; c += 8) {
      f4v w0 = *(const f4v*)(wr + c);
      f4v w1 = *(const f4v*)(wr + c + 4);
      f4v g0 = *(const f4v*)(nw_ + lc + c);
      f4v g1 = *(const f4v*)(nw_ + lc + c + 4);
      f4v b0 = *(const f4v*)(nb_ + lc + c);
      f4v b1 = *(const f4v*)(nb_ + lc + c + 4);
      float p[8];
      #pragma unroll
      for (int e = 0; e < 4; e++) {
        p[e]     = g0[e] * w0[e];
        p[4 + e] = g1[e] * w1[e];
        t1p += p[e] + p[4 + e];
        t2p += b0[e] * w0[e] + b1[e] * w1[e];
      }
      union { s8v v; unsigned u[4]; } o8;
      o8.u[0] = pack2bf(p[0], p[1]); o8.u[1] = pack2bf(p[2], p[3]);
      o8.u[2] = pack2bf(p[4], p[5]); o8.u[3] = pack2bf(p[6], p[7]);
      *(s8v*)(wpb + (size_t)j * 1024 + lc + c) = o8.v;
    }
    #pragma unroll
    for (int mm = 1; mm < 16; mm <<= 1) {
      t1p += __shfl_xor(t1p, mm, 64);
      t2p += __shfl_xor(t2p, mm, 64);
    }
    if ((threadIdx.x & 15) == 0) { t12[j * 2] = t1p; t12[j * 2 + 1] = t2p; }
  }
}

// ===== flash v10: KV-tile 128, 16 iters, 512-thread/8-wave blocks ===========
// Isolates iteration-count from occupancy: 2 blocks/CU x 8 waves = 16 waves/CU
// (same as r6) with HALF the barrier events. Per-wave per-iter issue matches
// r6 (36 MFMA, 32 ds_read_b128); acc state per thread halves (20 f32).
__global__ __launch_bounds__(512, 4) void flash_kernel(
    const float* __restrict__ xq, const float* __restrict__ qnw,
    const float* __restrict__ qnb, const short* __restrict__ kws,
    const short* __restrict__ vtp, short* __restrict__ aout,
    float* __restrict__ stp) {
  __shared__ __align__(16) union {
    char qs[128 * 144];                                 // 18432 B
    struct { char k[2][18432]; char v[2][20480]; } kv;  // 77824 B
  } lds;
  int blk = blockIdx.x;
  int sblk = blk & 15, bh = blk >> 4, b = bh >> 4;
  int t = threadIdx.x, wave = t >> 6, lane = t & 63;
  int m = lane & 15, q = lane >> 4;
  const float QSCALE = 0.125f * 1.4426950408889634f;  // scale * log2(e)

  const char* kb = (const char*)kws + (size_t)b * N_ * 144;
  const char* vb = (const char*)vtp + (size_t)b * 64 * 5120;

  // stage V tile 0 (disjoint from qs): 1280 chunks = 2 full + waves 0-3
  gld16(vb + t * 16, lds.kv.v[0] + t * 16);
  gld16(vb + (512 + t) * 16, lds.kv.v[0] + (512 + t) * 16);
  if (t < 256) gld16(vb + (1024 + t) * 16, lds.kv.v[0] + (1024 + t) * 16);

  // fused Q layernorm: 4 threads per row (t = 4r + c4), 2-step shfl combine
  {
    int r = t >> 2, c4 = t & 3;
    const float* qr = xq + ((size_t)bh * S_ + sblk * 128 + r) * 64 + c4 * 16;
    f4v f[4];
    float s = 0.f, ss = 0.f;
    #pragma unroll
    for (int i = 0; i < 4; i++) {
      f[i] = *(const f4v*)(qr + i * 4);
      s += (f[i][0] + f[i][1]) + (f[i][2] + f[i][3]);
      ss += (f[i][0] * f[i][0] + f[i][1] * f[i][1]) + (f[i][2] * f[i][2] + f[i][3] * f[i][3]);
    }
    s += __shfl_xor(s, 1, 64);  ss += __shfl_xor(ss, 1, 64);
    s += __shfl_xor(s, 2, 64);  ss += __shfl_xor(ss, 2, 64);
    float mean = s * 0.015625f;
    float rstd = rsqrtf(ss * 0.015625f - mean * mean + 1e-5f);
    #pragma unroll
    for (int i = 0; i < 2; i++) {          // s8v i covers elems c4*16+i*8..+8
      float y[8];
      #pragma unroll
      for (int e = 0; e < 4; e++) {
        int gi = c4 * 16 + i * 8;
        y[e]     = ((f[2 * i][e]     - mean) * rstd * qnw[gi + e]     + qnb[gi + e])     * QSCALE;
        y[4 + e] = ((f[2 * i + 1][e] - mean) * rstd * qnw[gi + 4 + e] + qnb[gi + 4 + e]) * QSCALE;
      }
      union { s8v v; unsigned u[4]; } o8;
      #pragma unroll
      for (int e = 0; e < 4; e++) o8.u[e] = pack2bf(y[2 * e], y[2 * e + 1]);
      *(s8v*)(lds.qs + r * 144 + c4 * 32 + i * 16) = o8.v;
    }
  }
  __syncthreads();

  // Q B-frags: wave owns rows [wave*16, wave*16+16)
  s8v qlo, qhi;
  {
    const char* qrow = lds.qs + (wave * 16 + m) * 144;
    qlo = *(const s8v*)(qrow + q * 16);
    qhi = *(const s8v*)(qrow + 64 + q * 16);
  }
  __syncthreads();  // all waves done reading qs; k[0] may be overwritten

  // stage K tile 0: 1152 chunks = 2 full + waves 0-1
  gld16(kb + t * 16, lds.kv.k[0] + t * 16);
  gld16(kb + (512 + t) * 16, lds.kv.k[0] + (512 + t) * 16);
  if (t < 128) gld16(kb + (1024 + t) * 16, lds.kv.k[0] + (1024 + t) * 16);
  __syncthreads();  // drains vmcnt(0): tile 0 resident

  f4v zero4 = {0.f, 0.f, 0.f, 0.f};
  f4v o[4], lacc = zero4;
  #pragma unroll
  for (int tt = 0; tt < 4; tt++) o[tt] = zero4;
  s8v ones;
  #pragma unroll
  for (int e = 0; e < 8; e++) ones[e] = (short)0x3F80;  // bf16 1.0

  for (int it = 0; it < 16; ++it) {
    int cur = it & 1;
    if (it < 15) {
      const char* kg = kb + (size_t)(it + 1) * 18432;
      const char* vg = vb + (size_t)(it + 1) * 20480;
      char* kd = lds.kv.k[cur ^ 1];
      char* vd = lds.kv.v[cur ^ 1];
      gld16(kg + t * 16, kd + t * 16);
      gld16(kg + (512 + t) * 16, kd + (512 + t) * 16);
      if (t < 128) gld16(kg + (1024 + t) * 16, kd + (1024 + t) * 16);
      gld16(vg + t * 16, vd + t * 16);
      gld16(vg + (512 + t) * 16, vd + (512 + t) * 16);
      if (t < 256) gld16(vg + (1024 + t) * 16, vd + (1024 + t) * 16);
    }
    const char* kc = lds.kv.k[cur];
    const char* vc = lds.kv.v[cur];

    #pragma unroll
    for (int g = 0; g < 4; g++) {
      s8v a0lo = *(const s8v*)(kc + (g * 32 + m) * 144 + q * 16);
      s8v a0hi = *(const s8v*)(kc + (g * 32 + m) * 144 + 64 + q * 16);
      s8v a1lo = *(const s8v*)(kc + (g * 32 + 16 + m) * 144 + q * 16);
      s8v a1hi = *(const s8v*)(kc + (g * 32 + 16 + m) * 144 + 64 + q * 16);
      s8v vf[4];
      #pragma unroll
      for (int tt = 0; tt < 4; tt++)
        vf[tt] = *(const s8v*)(vc + g * 5120 + (tt * 16 + m) * 80 + q * 16);

      f4v s0 = zero4, s1 = zero4;
      s0 = __builtin_amdgcn_mfma_f32_16x16x32_bf16(a0lo, qlo, s0, 0, 0, 0);
      s0 = __builtin_amdgcn_mfma_f32_16x16x32_bf16(a0hi, qhi, s0, 0, 0, 0);
      s1 = __builtin_amdgcn_mfma_f32_16x16x32_bf16(a1lo, qlo, s1, 0, 0, 0);
      s1 = __builtin_amdgcn_mfma_f32_16x16x32_bf16(a1hi, qhi, s1, 0, 0, 0);
      float p[8];
      #pragma unroll
      for (int i = 0; i < 4; i++) {
        // no clamp: LN'd q,k with 0.125 scale keep |s| << 128 (f32 exp2 range)
        p[i]     = __builtin_amdgcn_exp2f(s0[i]);
        p[4 + i] = __builtin_amdgcn_exp2f(s1[i]);
      }
      union { s8v v; unsigned u[4]; } pa;
      #pragma unroll
      for (int i = 0; i < 4; i++) pa.u[i] = pk2(p[2 * i], p[2 * i + 1]);
      lacc = __builtin_amdgcn_mfma_f32_16x16x32_bf16(pa.v, ones, lacc, 0, 0, 0);
      #pragma unroll
      for (int tt = 0; tt < 4; tt++)
        o[tt] = __builtin_amdgcn_mfma_f32_16x16x32_bf16(pa.v, vf[tt], o[tt], 0, 0, 0);
    }
    // single barrier: drains next tile's DMA + fences buffer reuse
    __syncthreads();
  }

  // epilogue: write bf16 + per-(row,head) stats partial (no atomics)
  int head = bh & 15;
  #pragma unroll
  for (int i = 0; i < 4; i++) {
    float inv = __builtin_amdgcn_rcpf(lacc[i]);
    int srow = sblk * 128 + wave * 16 + q * 4 + i;
    size_t orow = ((size_t)b * S_ + srow) * D_ + (size_t)head * 64;
    float ps = 0.f, pss = 0.f;
    #pragma unroll
    for (int tt = 0; tt < 4; tt++) {
      float v = o[tt][i] * inv;
      ps += v; pss += v * v;
      aout[orow + tt * 16 + m] = f2bf(v);
    }
    #pragma unroll
    for (int mm = 1; mm < 16; mm <<= 1) {
      ps += __shfl_xor(ps, mm, 64);
      pss += __shfl_xor(pss, mm, 64);
    }
    if (m == 0) {
      size_t gr = (size_t)b * S_ + srow;
      f2v pv = {ps, pss};
      *(f2v*)(stp + (gr * 16 + head) * 2) = pv;
    }
  }
}

// ===== LN over D=1024 (fallback path only) ==================================
__global__ __launch_bounds__(256) void ln_d_kernel(
    const short* __restrict__ x, const float* __restrict__ w,
    const float* __restrict__ bb, short* __restrict__ y) {
  int row = blockIdx.x * 4 + (threadIdx.x >> 6);
  int lane = threadIdx.x & 63;
  const short* xr = x + (size_t)row * D_ + lane * 16;
  s8v v0 = *(const s8v*)xr;
  s8v v1 = *(const s8v*)(xr + 8);
  float f[16];
  #pragma unroll
  for (int e = 0; e < 8; e++) { f[e] = bf2f(v0[e]); f[8 + e] = bf2f(v1[e]); }
  float s = 0.f, ss = 0.f;
  #pragma unroll
  for (int e = 0; e < 16; e++) { s += f[e]; ss += f[e] * f[e]; }
  #pragma unroll
  for (int mm = 1; mm < 64; mm <<= 1) {
    s += __shfl_xor(s, mm, 64);
    ss += __shfl_xor(ss, mm, 64);
  }
  float mean = s * (1.0f / 1024.0f);
  float rstd = rsqrtf(ss * (1.0f / 1024.0f) - mean * mean + 1e-5f);
  const float* wp = w + lane * 16;
  const float* bp = bb + lane * 16;
  union { s8v v[2]; short sh[16]; } o;
  #pragma unroll
  for (int e = 0; e < 16; e++)
    o.sh[e] = f2bf((f[e] - mean) * rstd * wp[e] + bp[e]);
  short* yr = y + (size_t)row * D_ + lane * 16;
  *(s8v*)yr = o.v[0];
  *(s8v*)(yr + 8) = o.v[1];
}

// ===== proj (fallback, r3 verbatim): C = Y * W^T =============================
__global__ __launch_bounds__(256, 2) void proj_gemm_fb(
    const short* __restrict__ A, const float* __restrict__ Bw,
    float* __restrict__ C) {
  __shared__ __align__(16) char la[2][16384];
  __shared__ __align__(16) char lb[2][16384];
  int wg = (blockIdx.x & 7) * 64 + (blockIdx.x >> 3);
  int bm = (wg >> 3) * 128;
  int bn = (wg & 7) * 128;
  int t = threadIdx.x, wave = t >> 6, lane = t & 63;
  int m = lane & 15, q = lane >> 4;
  int wm = (wave & 1) * 64, wn = (wave >> 1) * 64;

  int arow0 = t >> 3, au = t & 7;
  const char* abase = (const char*)(A + (size_t)bm * 1024);
  int brow = t >> 1, bu0 = (t & 1) * 4;
  const float* bwbase = Bw + (size_t)(bn + brow) * 1024;
  char* lbrow0 = lb[0] + brow * 128;
  char* lbrow1 = lb[1] + brow * 128;

  f4v zero4 = {0.f, 0.f, 0.f, 0.f};
  f4v acc[4][4];
  #pragma unroll
  for (int i = 0; i < 4; i++)
    #pragma unroll
    for (int j = 0; j < 4; j++) acc[i][j] = zero4;

  #pragma unroll
  for (int c = 0; c < 4; c++) {
    int row = c * 32 + arow0;
    gld16(abase + (size_t)row * 2048 + (size_t)(au ^ (row & 7)) * 16,
          la[0] + c * 4096 + t * 16);
  }
  #pragma unroll
  for (int j = 0; j < 4; j++) {
    int u = bu0 + j;
    s8v bv = load8f32(bwbase + u * 8);
    *(s8v*)(lbrow0 + ((u ^ (brow & 7)) * 16)) = bv;
  }
  __syncthreads();

  for (int it = 0; it < 16; ++it) {
    int cur = it & 1;
    if (it < 15) {
      int k0 = (it + 1) * 64;
      char* ad = la[cur ^ 1];
      char* bd = (cur ^ 1) ? lbrow1 : lbrow0;
      #pragma unroll
      for (int c = 0; c < 4; c++) {
        int row = c * 32 + arow0;
        gld16(abase + (size_t)row * 2048 + (size_t)k0 * 2 +
                  (size_t)(au ^ (row & 7)) * 16,
              ad + c * 4096 + t * 16);
      }
      #pragma unroll
      for (int j = 0; j < 4; j++) {
        int u = bu0 + j;
        s8v bv = load8f32(bwbase + k0 + u * 8);
        *(s8v*)(bd + ((u ^ (brow & 7)) * 16)) = bv;
      }
    }
    const char* lac = la[cur];
    const char* lbc = lb[cur];
    #pragma unroll
    for (int kh = 0; kh < 2; kh++) {
      s8v af[4], bfv[4];
      #pragma unroll
      for (int i = 0; i < 4; i++) {
        int r = wm + i * 16 + m;
        af[i] = *(const s8v*)(lac + r * 128 + (((kh * 4 + q) ^ (r & 7)) * 16));
      }
      #pragma unroll
      for (int j = 0; j < 4; j++) {
        int r = wn + j * 16 + m;
        bfv[j] = *(const s8v*)(lbc + r * 128 + (((kh * 4 + q) ^ (r & 7)) * 16));
      }
      #pragma unroll
      for (int i = 0; i < 4; i++)
        #pragma unroll
        for (int j = 0; j < 4; j++)
          acc[i][j] = __builtin_amdgcn_mfma_f32_16x16x32_bf16(af[i], bfv[j], acc[i][j], 0, 0, 0);
    }
    __syncthreads();
  }

  #pragma unroll
  for (int i = 0; i < 4; i++)
    #pragma unroll
    for (int j = 0; j < 4; j++)
      #pragma unroll
      for (int r = 0; r < 4; r++) {
        int row = bm + wm + i * 16 + q * 4 + r;
        int col = bn + wn + j * 16 + m;
        C[(size_t)row * 1024 + col] = acc[i][j][r];
      }
}

// ===== proj (fused): C = rs*(A.W'^T) + mrs*t1 + t2; head-partials reduce ====
__global__ __launch_bounds__(256, 2) void proj_gemm_fx(
    const short* __restrict__ A, const short* __restrict__ Wp,
    const float* __restrict__ t12, const float* __restrict__ stp,
    float* __restrict__ C) {
  __shared__ __align__(16) char la[2][16384];
  __shared__ __align__(16) char lb[2][16384];
  int wg = (blockIdx.x & 7) * 64 + (blockIdx.x >> 3);
  int bm = (wg >> 3) * 128;
  int bn = (wg & 7) * 128;
  int t = threadIdx.x, wave = t >> 6, lane = t & 63;
  int m = lane & 15, q = lane >> 4;
  int wm = (wave & 1) * 64, wn = (wave >> 1) * 64;

  int arow0 = t >> 3, au = t & 7;
  const char* abase = (const char*)(A + (size_t)bm * 1024);
  const char* bbase = (const char*)(Wp + (size_t)bn * 1024);

  f4v zero4 = {0.f, 0.f, 0.f, 0.f};
  f4v acc[4][4];
  #pragma unroll
  for (int i = 0; i < 4; i++)
    #pragma unroll
    for (int j = 0; j < 4; j++) acc[i][j] = zero4;

  #pragma unroll
  for (int c = 0; c < 4; c++) {
    int row = c * 32 + arow0;
    size_t so = (size_t)row * 2048 + (size_t)(au ^ (row & 7)) * 16;
    gld16(abase + so, la[0] + c * 4096 + t * 16);
    gld16(bbase + so, lb[0] + c * 4096 + t * 16);
  }
  __syncthreads();

  for (int it = 0; it < 16; ++it) {
    int cur = it & 1;
    if (it < 15) {
      int k0 = (it + 1) * 64;
      #pragma unroll
      for (int c = 0; c < 4; c++) {
        int row = c * 32 + arow0;
        size_t so = (size_t)row * 2048 + (size_t)k0 * 2 +
                    (size_t)(au ^ (row & 7)) * 16;
        gld16(abase + so, la[cur ^ 1] + c * 4096 + t * 16);
        gld16(bbase + so, lb[cur ^ 1] + c * 4096 + t * 16);
      }
    }
    const char* lac = la[cur];
    const char* lbc = lb[cur];
    #pragma unroll
    for (int kh = 0; kh < 2; kh++) {
      s8v af[4], bfv[4];
      #pragma unroll
      for (int i = 0; i < 4; i++) {
        int r = wm + i * 16 + m;
        af[i] = *(const s8v*)(lac + r * 128 + (((kh * 4 + q) ^ (r & 7)) * 16));
      }
      #pragma unroll
      for (int j = 0; j < 4; j++) {
        int r = wn + j * 16 + m;
        bfv[j] = *(const s8v*)(lbc + r * 128 + (((kh * 4 + q) ^ (r & 7)) * 16));
      }
      #pragma unroll
      for (int i = 0; i < 4; i++)
        #pragma unroll
        for (int j = 0; j < 4; j++)
          acc[i][j] = __builtin_amdgcn_mfma_f32_16x16x32_bf16(af[i], bfv[j], acc[i][j], 0, 0, 0);
    }
    __syncthreads();
  }

  f2v tc[4];
  #pragma unroll
  for (int j = 0; j < 4; j++)
    tc[j] = *(const f2v*)(t12 + (size_t)(bn + wn + j * 16 + m) * 2);
  #pragma unroll
  for (int i = 0; i < 4; i++)
    #pragma unroll
    for (int r = 0; r < 4; r++) {
      int row = bm + wm + i * 16 + q * 4 + r;
      // reduce 16 per-head partials: lane m loads head m's (s,ss), butterfly
      f2v pp = *(const f2v*)(stp + ((size_t)row * 16 + m) * 2);
      float s_ = pp[0], ss_ = pp[1];
      #pragma unroll
      for (int mm = 1; mm < 16; mm <<= 1) {
        s_ += __shfl_xor(s_, mm, 64);
        ss_ += __shfl_xor(ss_, mm, 64);
      }
      float mean = s_ * (1.0f / 1024.0f);
      float rstd = rsqrtf(ss_ * (1.0f / 1024.0f) - mean * mean + 1e-5f);
      float mrs = -mean * rstd;
      #pragma unroll
      for (int j = 0; j < 4; j++) {
        int col = bn + wn + j * 16 + m;
        C[(size_t)row * 1024 + col] =
            rstd * acc[i][j][r] + mrs * tc[j][0] + tc[j][1];
      }
    }
}

extern "C" void kernel_launch(void* const* d_in, const int* in_sizes, int n_in,
                              void* d_out, int out_size, void* d_ws, size_t ws_size,
                              hipStream_t stream) {
  const float* xq  = (const float*)d_in[0];
  const float* xk  = (const float*)d_in[1];
  const float* xv  = (const float*)d_in[2];
  const float* qnw = (const float*)d_in[3];
  const float* qnb = (const float*)d_in[4];
  const float* knw = (const float*)d_in[5];
  const float* knb = (const float*)d_in[6];
  const float* nw  = (const float*)d_in[7];
  const float* nb  = (const float*)d_in[8];
  const float* pw  = (const float*)d_in[9];
  float* out = (float*)d_out;

  const size_t NEED = 22421504;  // aout + kws + vtp + W' + t12 + stp(1MB)
  if (ws_size >= NEED) {
    // fused path: final LN folded into proj epilogue; flash writes per-head
    // (s,ss) partials (no atomics); proj reduces 16 heads via lane-butterfly.
    short* aoutw = (short*)d_ws;
    short* kws = (short*)((char*)d_ws + 16777216);
    short* vtp = (short*)((char*)d_ws + 17956864);
    short* wpb = (short*)((char*)d_ws + 19267584);
    float* t12 = (float*)((char*)d_ws + 21364736);
    float* stp = (float*)((char*)d_ws + 21372928);
    prep_kernel<<<2176, 256, 0, stream>>>(xk, knw, knb, kws, xv, vtp,
                                          pw, nw, nb, wpb, t12);
    flash_kernel<<<1024, 512, 0, stream>>>(xq, qnw, qnb, kws, vtp, aoutw, stp);
    proj_gemm_fx<<<512, 256, 0, stream>>>(aoutw, wpb, t12, stp, out);
  } else {
    // fallback: r3 pipeline; stats partials land in dead back half of d_out
    short* kws = (short*)d_ws;
    short* vtp = (short*)((char*)d_ws + 0x120000);
    short* yws = (short*)d_ws;
    short* aout = (short*)d_out;
    float* stdummy = (float*)((char*)d_out + 20971520);
    prep_kernel<<<2112, 256, 0, stream>>>(xk, knw, knb, kws, xv, vtp,
                                          pw, nw, nb, (short*)d_ws, (float*)d_ws);
    flash_kernel<<<1024, 512, 0, stream>>>(xq, qnw, qnb, kws, vtp, aout, stdummy);
    ln_d_kernel<<<B_ * S_ / 4, 256, 0, stream>>>(aout, nw, nb, yws);
    proj_gemm_fb<<<512, 256, 0, stream>>>(yws, pw, out);
  }
}

// Round 11
// 197.353 us; speedup vs baseline: 1.0492x; 1.0492x over previous
//
#include <hip/hip_runtime.h>

#define B_ 4
#define S_ 2048
#define N_ 2048
#define H_ 16
#define D_ 1024

typedef short s4v __attribute__((ext_vector_type(4)));
typedef short s8v __attribute__((ext_vector_type(8)));
typedef float f4v __attribute__((ext_vector_type(4)));
typedef float f2v __attribute__((ext_vector_type(2)));

__device__ __forceinline__ float bf2f(short s) {
  unsigned u = ((unsigned)(unsigned short)s) << 16;
  float f; __builtin_memcpy(&f, &u, 4); return f;
}
__device__ __forceinline__ short f2bf(float f) {
  unsigned u; __builtin_memcpy(&u, &f, 4);
  u += 0x7fffu + ((u >> 16) & 1u);
  return (short)(u >> 16);
}
__device__ __forceinline__ unsigned pack2bf(float a, float b) {
  unsigned ua, ub;
  __builtin_memcpy(&ua, &a, 4);
  __builtin_memcpy(&ub, &b, 4);
  return __builtin_amdgcn_perm(ub + 0x8000u, ua + 0x8000u, 0x07060302u);
}
// truncating pack (P values; bias cancels in softmax ratio num/denom)
__device__ __forceinline__ unsigned pk2(float a, float b) {
  unsigned ua, ub;
  __builtin_memcpy(&ua, &a, 4);
  __builtin_memcpy(&ub, &b, 4);
  return __builtin_amdgcn_perm(ub, ua, 0x07060302u);
}
__device__ __forceinline__ s8v load8f32(const float* p) {
  const f4v* q = (const f4v*)p;
  f4v a = q[0], b = q[1];
  union { s8v v; unsigned u[4]; } o;
  o.u[0] = pack2bf(a[0], a[1]); o.u[1] = pack2bf(a[2], a[3]);
  o.u[2] = pack2bf(b[0], b[1]); o.u[3] = pack2bf(b[2], b[3]);
  return o.v;
}
// async global->LDS, 16B per lane. LDS dest must be wave-uniform base + lane*16.
__device__ __forceinline__ void gld16(const char* g, char* l) {
  __builtin_amdgcn_global_load_lds(
      (const __attribute__((address_space(1))) unsigned*)g,
      (__attribute__((address_space(3))) unsigned*)l, 16, 0, 0);
}

// ===== prep: K-LN (144-B rows) + V transpose (80-B rows) + W' fold ==========
__global__ __launch_bounds__(256) void prep_kernel(
    const float* __restrict__ xk, const float* __restrict__ knw,
    const float* __restrict__ knb, short* __restrict__ kws,
    const float* __restrict__ xv, short* __restrict__ vtp,
    const float* __restrict__ pw, const float* __restrict__ nw_,
    const float* __restrict__ nb_, short* __restrict__ wpb,
    float* __restrict__ t12) {
  __shared__ __align__(16) short vstage[4][2048];
  int blk = blockIdx.x;
  if (blk < 2048) {
    int gid = blk * 256 + threadIdx.x;
    int row = gid >> 6, lane = gid & 63;
    float v = xk[(size_t)row * 64 + lane];
    float s = v;
    #pragma unroll
    for (int mm = 1; mm < 64; mm <<= 1) s += __shfl_xor(s, mm, 64);
    float mean = s * 0.015625f;
    float d = v - mean;
    float vs = d * d;
    #pragma unroll
    for (int mm = 1; mm < 64; mm <<= 1) vs += __shfl_xor(vs, mm, 64);
    float rstd = rsqrtf(vs * 0.015625f + 1e-5f);
    kws[(size_t)row * 72 + lane] = f2bf(d * rstd * knw[lane] + knb[lane]);
  } else if (blk < 2112) {
    int wave = threadIdx.x >> 6, lane = threadIdx.x & 63;
    int u = (blk - 2048) * 4 + wave;        // (b,nb) unit, 0..255
    int b = u >> 6, nb = u & 63;
    int r = lane >> 1, dh = lane & 1;       // V row within 32-block, d-half
    const float* src = xv + ((size_t)(b * N_ + nb * 32 + r)) * 64 + dh * 32;
    int qq = (r & 15) >> 2;
    int slot = ((r >> 4) << 2) + (r & 3);
    short* wbase = &vstage[wave][0];
    #pragma unroll
    for (int jj = 0; jj < 32; jj += 4) {
      f4v f = *(const f4v*)(src + jj);
      #pragma unroll
      for (int e = 0; e < 4; e++) {
        int d = dh * 32 + jj + e;
        wbase[d * 32 + qq * 8 + slot] = f2bf(f[e]);
      }
    }
    __syncthreads();
    // padded: unit stride 2560 shorts (5120 B), d-row stride 40 shorts (80 B)
    s8v* dst = (s8v*)(vtp + (size_t)u * 2560 + lane * 40);
    const s8v* sp = (const s8v*)(wbase + lane * 32);
    dst[0] = sp[0]; dst[1] = sp[1]; dst[2] = sp[2]; dst[3] = sp[3];
  } else {
    // W' builder: W'_jk = bf16(nw_k*W_jk); t1_j = sum nw_k W_jk; t2_j = sum nb_k W_jk
    int jr = threadIdx.x >> 4;
    int lc = (threadIdx.x & 15) * 64;
    int j = (blk - 2112) * 16 + jr;
    const float* wr = pw + (size_t)j * 1024 + lc;
    float t1p = 0.f, t2p = 0.f;
    #pragma unroll
    for (int c = 0; c < 64; c += 8) {
      f4v w0 = *(const f4v*)(wr + c);
      f4v w1 = *(const f4v*)(wr + c + 4);
      f4v g0 = *(const f4v*)(nw_ + lc + c);
      f4v g1 = *(const f4v*)(nw_ + lc + c + 4);
      f4v b0 = *(const f4v*)(nb_ + lc + c);
      f4v b1 = *(const f4v*)(nb_ + lc + c + 4);
      float p[8];
      #pragma unroll
      for (int e = 0; e < 4; e++) {
        p[e]     = g0[e] * w0[e];
        p[4 + e] = g1[e] * w1[e];
        t1p += p[e] + p[4 + e];
        t2p += b0[e] * w0[e] + b1[e] * w1[e];
      }
      union { s8v v; unsigned u[4]; } o8;
      o8.u[0] = pack2bf(p[0], p[1]); o8.u[1] = pack2bf(p[2], p[3]);
      o8.u[2] = pack2bf(p[4], p[5]); o8.u[3] = pack2bf(p[6], p[7]);
      *(s8v*)(wpb + (size_t)j * 1024 + lc + c) = o8.v;
    }
    #pragma unroll
    for (int mm = 1; mm < 16; mm <<= 1) {
      t1p += __shfl_xor(t1p, mm, 64);
      t2p += __shfl_xor(t2p, mm, 64);
    }
    if ((threadIdx.x & 15) == 0) { t12[j * 2] = t1p; t12[j * 2 + 1] = t2p; }
  }
}

// ===== flash v6 (RESTORED r6 optimum): 128 q-rows, KV-tile 64, 4 blocks/CU ==
// r6 sits at a three-constraint vertex (VGPR=64 boundary, LDS 4-block
// boundary, 2 m-tiles/wave amortization). All neighbors measured worse:
// tile 32 (r8) 102us, tile 128@2blk (r9) 88.5, 16rows/wave@16w (r10) 96.6,
// stagger/setprio (r5) 86, counted-vmcnt (r7) 87.
__global__ __launch_bounds__(256, 4) void flash_kernel(
    const float* __restrict__ xq, const float* __restrict__ qnw,
    const float* __restrict__ qnb, const short* __restrict__ kws,
    const short* __restrict__ vtp, short* __restrict__ aout,
    float* __restrict__ stp) {
  __shared__ __align__(16) union {
    char qs[128 * 144];                               // 18432 B
    struct { char k[2][9216]; char v[2][10240]; } kv; // 38912 B
  } lds;
  int blk = blockIdx.x;
  int sblk = blk & 15, bh = blk >> 4, b = bh >> 4;
  int t = threadIdx.x, wave = t >> 6, lane = t & 63;
  int m = lane & 15, q = lane >> 4;
  const float QSCALE = 0.125f * 1.4426950408889634f;  // scale * log2(e)

  const char* kb = (const char*)kws + (size_t)b * N_ * 144;
  const char* vb = (const char*)vtp + (size_t)b * 64 * 5120;

  gld16(vb + t * 16,        lds.kv.v[0] + t * 16);
  gld16(vb + 4096 + t * 16, lds.kv.v[0] + 4096 + t * 16);
  if (t < 128) gld16(vb + 8192 + t * 16, lds.kv.v[0] + 8192 + t * 16);

  // fused Q layernorm: 2 threads per row (t=2r+half), pair-combine via shfl
  {
    int r = t >> 1, half = t & 1;
    const float* qr = xq + ((size_t)bh * S_ + sblk * 128 + r) * 64 + half * 32;
    f4v f[8];
    float s = 0.f, ss = 0.f;
    #pragma unroll
    for (int i = 0; i < 8; i++) {
      f[i] = *(const f4v*)(qr + i * 4);
      s += (f[i][0] + f[i][1]) + (f[i][2] + f[i][3]);
      ss += (f[i][0] * f[i][0] + f[i][1] * f[i][1]) + (f[i][2] * f[i][2] + f[i][3] * f[i][3]);
    }
    s += __shfl_xor(s, 1, 64);
    ss += __shfl_xor(ss, 1, 64);
    float mean = s * 0.015625f;
    float rstd = rsqrtf(ss * 0.015625f - mean * mean + 1e-5f);
    #pragma unroll
    for (int i = 0; i < 4; i++) {          // s8v i covers elems half*32+i*8..+8
      float y[8];
      #pragma unroll
      for (int e = 0; e < 4; e++) {
        int gi = half * 32 + i * 8;
        y[e]     = ((f[2 * i][e]     - mean) * rstd * qnw[gi + e]     + qnb[gi + e])     * QSCALE;
        y[4 + e] = ((f[2 * i + 1][e] - mean) * rstd * qnw[gi + 4 + e] + qnb[gi + 4 + e]) * QSCALE;
      }
      union { s8v v; unsigned u[4]; } o8;
      #pragma unroll
      for (int e = 0; e < 4; e++) o8.u[e] = pack2bf(y[2 * e], y[2 * e + 1]);
      *(s8v*)(lds.qs + r * 144 + half * 64 + i * 16) = o8.v;
    }
  }
  __syncthreads();

  s8v qlo[2], qhi[2];
  #pragma unroll
  for (int mt = 0; mt < 2; mt++) {
    const char* qrow = lds.qs + (wave * 32 + mt * 16 + m) * 144;
    qlo[mt] = *(const s8v*)(qrow + q * 16);
    qhi[mt] = *(const s8v*)(qrow + 64 + q * 16);
  }
  __syncthreads();  // all waves done reading qs; k[0]/k[1] may be overwritten

  gld16(kb + t * 16,        lds.kv.k[0] + t * 16);
  gld16(kb + 4096 + t * 16, lds.kv.k[0] + 4096 + t * 16);
  if (t < 64) gld16(kb + 8192 + t * 16, lds.kv.k[0] + 8192 + t * 16);
  __syncthreads();  // compiler drains vmcnt(0) here: tile 0 resident

  f4v zero4 = {0.f, 0.f, 0.f, 0.f};
  f4v o[2][4], lacc[2];
  #pragma unroll
  for (int mt = 0; mt < 2; mt++) {
    lacc[mt] = zero4;
    #pragma unroll
    for (int tt = 0; tt < 4; tt++) o[mt][tt] = zero4;
  }
  s8v ones;
  #pragma unroll
  for (int e = 0; e < 8; e++) ones[e] = (short)0x3F80;  // bf16 1.0

  for (int it = 0; it < 32; ++it) {
    int cur = it & 1;
    if (it < 31) {
      const char* kg = kb + (size_t)(it + 1) * 9216;
      const char* vg = vb + (size_t)(it + 1) * 10240;
      char* kd = lds.kv.k[cur ^ 1];
      char* vd = lds.kv.v[cur ^ 1];
      gld16(kg + t * 16,        kd + t * 16);
      gld16(kg + 4096 + t * 16, kd + 4096 + t * 16);
      if (t < 64) gld16(kg + 8192 + t * 16, kd + 8192 + t * 16);
      gld16(vg + t * 16,        vd + t * 16);
      gld16(vg + 4096 + t * 16, vd + 4096 + t * 16);
      if (t < 128) gld16(vg + 8192 + t * 16, vd + 8192 + t * 16);
    }
    const char* kc = lds.kv.k[cur];
    const char* vc = lds.kv.v[cur];

    #pragma unroll
    for (int g = 0; g < 2; g++) {
      s8v a0lo = *(const s8v*)(kc + (g * 32 + m) * 144 + q * 16);
      s8v a0hi = *(const s8v*)(kc + (g * 32 + m) * 144 + 64 + q * 16);
      s8v a1lo = *(const s8v*)(kc + (g * 32 + 16 + m) * 144 + q * 16);
      s8v a1hi = *(const s8v*)(kc + (g * 32 + 16 + m) * 144 + 64 + q * 16);
      s8v vf[4];
      #pragma unroll
      for (int tt = 0; tt < 4; tt++)
        vf[tt] = *(const s8v*)(vc + g * 5120 + (tt * 16 + m) * 80 + q * 16);

      #pragma unroll
      for (int mt = 0; mt < 2; mt++) {
        f4v s0 = zero4, s1 = zero4;
        s0 = __builtin_amdgcn_mfma_f32_16x16x32_bf16(a0lo, qlo[mt], s0, 0, 0, 0);
        s0 = __builtin_amdgcn_mfma_f32_16x16x32_bf16(a0hi, qhi[mt], s0, 0, 0, 0);
        s1 = __builtin_amdgcn_mfma_f32_16x16x32_bf16(a1lo, qlo[mt], s1, 0, 0, 0);
        s1 = __builtin_amdgcn_mfma_f32_16x16x32_bf16(a1hi, qhi[mt], s1, 0, 0, 0);
        float p[8];
        #pragma unroll
        for (int i = 0; i < 4; i++) {
          // no clamp: LN'd q,k with 0.125 scale keep |s| << 128 (f32 exp2 range)
          p[i]     = __builtin_amdgcn_exp2f(s0[i]);
          p[4 + i] = __builtin_amdgcn_exp2f(s1[i]);
        }
        union { s8v v; unsigned u[4]; } pa;
        #pragma unroll
        for (int i = 0; i < 4; i++) pa.u[i] = pk2(p[2 * i], p[2 * i + 1]);
        lacc[mt] = __builtin_amdgcn_mfma_f32_16x16x32_bf16(pa.v, ones, lacc[mt], 0, 0, 0);
        #pragma unroll
        for (int tt = 0; tt < 4; tt++)
          o[mt][tt] = __builtin_amdgcn_mfma_f32_16x16x32_bf16(pa.v, vf[tt], o[mt][tt], 0, 0, 0);
      }
    }
    __syncthreads();
  }

  // epilogue: write bf16 + per-(row,head) stats partial (no atomics):
  // m-group (16 lanes) holds this head's 64 cols of one row -> 4x shfl_xor,
  // lane m==0 stores f2v to stp[row*16 + head]
  int head = bh & 15;
  #pragma unroll
  for (int mt = 0; mt < 2; mt++) {
    #pragma unroll
    for (int i = 0; i < 4; i++) {
      float inv = __builtin_amdgcn_rcpf(lacc[mt][i]);
      int srow = sblk * 128 + wave * 32 + mt * 16 + q * 4 + i;
      size_t orow = ((size_t)b * S_ + srow) * D_ + (size_t)head * 64;
      float ps = 0.f, pss = 0.f;
      #pragma unroll
      for (int tt = 0; tt < 4; tt++) {
        float v = o[mt][tt][i] * inv;
        ps += v; pss += v * v;
        aout[orow + tt * 16 + m] = f2bf(v);
      }
      #pragma unroll
      for (int mm = 1; mm < 16; mm <<= 1) {
        ps += __shfl_xor(ps, mm, 64);
        pss += __shfl_xor(pss, mm, 64);
      }
      if (m == 0) {
        size_t gr = (size_t)b * S_ + srow;
        f2v pv = {ps, pss};
        *(f2v*)(stp + (gr * 16 + head) * 2) = pv;
      }
    }
  }
}

// ===== LN over D=1024 (fallback path only) ==================================
__global__ __launch_bounds__(256) void ln_d_kernel(
    const short* __restrict__ x, const float* __restrict__ w,
    const float* __restrict__ bb, short* __restrict__ y) {
  int row = blockIdx.x * 4 + (threadIdx.x >> 6);
  int lane = threadIdx.x & 63;
  const short* xr = x + (size_t)row * D_ + lane * 16;
  s8v v0 = *(const s8v*)xr;
  s8v v1 = *(const s8v*)(xr + 8);
  float f[16];
  #pragma unroll
  for (int e = 0; e < 8; e++) { f[e] = bf2f(v0[e]); f[8 + e] = bf2f(v1[e]); }
  float s = 0.f, ss = 0.f;
  #pragma unroll
  for (int e = 0; e < 16; e++) { s += f[e]; ss += f[e] * f[e]; }
  #pragma unroll
  for (int mm = 1; mm < 64; mm <<= 1) {
    s += __shfl_xor(s, mm, 64);
    ss += __shfl_xor(ss, mm, 64);
  }
  float mean = s * (1.0f / 1024.0f);
  float rstd = rsqrtf(ss * (1.0f / 1024.0f) - mean * mean + 1e-5f);
  const float* wp = w + lane * 16;
  const float* bp = bb + lane * 16;
  union { s8v v[2]; short sh[16]; } o;
  #pragma unroll
  for (int e = 0; e < 16; e++)
    o.sh[e] = f2bf((f[e] - mean) * rstd * wp[e] + bp[e]);
  short* yr = y + (size_t)row * D_ + lane * 16;
  *(s8v*)yr = o.v[0];
  *(s8v*)(yr + 8) = o.v[1];
}

// ===== proj (fallback, r3 verbatim): C = Y * W^T =============================
__global__ __launch_bounds__(256, 2) void proj_gemm_fb(
    const short* __restrict__ A, const float* __restrict__ Bw,
    float* __restrict__ C) {
  __shared__ __align__(16) char la[2][16384];
  __shared__ __align__(16) char lb[2][16384];
  int wg = (blockIdx.x & 7) * 64 + (blockIdx.x >> 3);
  int bm = (wg >> 3) * 128;
  int bn = (wg & 7) * 128;
  int t = threadIdx.x, wave = t >> 6, lane = t & 63;
  int m = lane & 15, q = lane >> 4;
  int wm = (wave & 1) * 64, wn = (wave >> 1) * 64;

  int arow0 = t >> 3, au = t & 7;
  const char* abase = (const char*)(A + (size_t)bm * 1024);
  int brow = t >> 1, bu0 = (t & 1) * 4;
  const float* bwbase = Bw + (size_t)(bn + brow) * 1024;
  char* lbrow0 = lb[0] + brow * 128;
  char* lbrow1 = lb[1] + brow * 128;

  f4v zero4 = {0.f, 0.f, 0.f, 0.f};
  f4v acc[4][4];
  #pragma unroll
  for (int i = 0; i < 4; i++)
    #pragma unroll
    for (int j = 0; j < 4; j++) acc[i][j] = zero4;

  #pragma unroll
  for (int c = 0; c < 4; c++) {
    int row = c * 32 + arow0;
    gld16(abase + (size_t)row * 2048 + (size_t)(au ^ (row & 7)) * 16,
          la[0] + c * 4096 + t * 16);
  }
  #pragma unroll
  for (int j = 0; j < 4; j++) {
    int u = bu0 + j;
    s8v bv = load8f32(bwbase + u * 8);
    *(s8v*)(lbrow0 + ((u ^ (brow & 7)) * 16)) = bv;
  }
  __syncthreads();

  for (int it = 0; it < 16; ++it) {
    int cur = it & 1;
    if (it < 15) {
      int k0 = (it + 1) * 64;
      char* ad = la[cur ^ 1];
      char* bd = (cur ^ 1) ? lbrow1 : lbrow0;
      #pragma unroll
      for (int c = 0; c < 4; c++) {
        int row = c * 32 + arow0;
        gld16(abase + (size_t)row * 2048 + (size_t)k0 * 2 +
                  (size_t)(au ^ (row & 7)) * 16,
              ad + c * 4096 + t * 16);
      }
      #pragma unroll
      for (int j = 0; j < 4; j++) {
        int u = bu0 + j;
        s8v bv = load8f32(bwbase + k0 + u * 8);
        *(s8v*)(bd + ((u ^ (brow & 7)) * 16)) = bv;
      }
    }
    const char* lac = la[cur];
    const char* lbc = lb[cur];
    #pragma unroll
    for (int kh = 0; kh < 2; kh++) {
      s8v af[4], bfv[4];
      #pragma unroll
      for (int i = 0; i < 4; i++) {
        int r = wm + i * 16 + m;
        af[i] = *(const s8v*)(lac + r * 128 + (((kh * 4 + q) ^ (r & 7)) * 16));
      }
      #pragma unroll
      for (int j = 0; j < 4; j++) {
        int r = wn + j * 16 + m;
        bfv[j] = *(const s8v*)(lbc + r * 128 + (((kh * 4 + q) ^ (r & 7)) * 16));
      }
      #pragma unroll
      for (int i = 0; i < 4; i++)
        #pragma unroll
        for (int j = 0; j < 4; j++)
          acc[i][j] = __builtin_amdgcn_mfma_f32_16x16x32_bf16(af[i], bfv[j], acc[i][j], 0, 0, 0);
    }
    __syncthreads();
  }

  #pragma unroll
  for (int i = 0; i < 4; i++)
    #pragma unroll
    for (int j = 0; j < 4; j++)
      #pragma unroll
      for (int r = 0; r < 4; r++) {
        int row = bm + wm + i * 16 + q * 4 + r;
        int col = bn + wn + j * 16 + m;
        C[(size_t)row * 1024 + col] = acc[i][j][r];
      }
}

// ===== proj (fused): C = rs*(A.W'^T) + mrs*t1 + t2; head-partials reduce ====
__global__ __launch_bounds__(256, 2) void proj_gemm_fx(
    const short* __restrict__ A, const short* __restrict__ Wp,
    const float* __restrict__ t12, const float* __restrict__ stp,
    float* __restrict__ C) {
  __shared__ __align__(16) char la[2][16384];
  __shared__ __align__(16) char lb[2][16384];
  int wg = (blockIdx.x & 7) * 64 + (blockIdx.x >> 3);
  int bm = (wg >> 3) * 128;
  int bn = (wg & 7) * 128;
  int t = threadIdx.x, wave = t >> 6, lane = t & 63;
  int m = lane & 15, q = lane >> 4;
  int wm = (wave & 1) * 64, wn = (wave >> 1) * 64;

  int arow0 = t >> 3, au = t & 7;
  const char* abase = (const char*)(A + (size_t)bm * 1024);
  const char* bbase = (const char*)(Wp + (size_t)bn * 1024);

  f4v zero4 = {0.f, 0.f, 0.f, 0.f};
  f4v acc[4][4];
  #pragma unroll
  for (int i = 0; i < 4; i++)
    #pragma unroll
    for (int j = 0; j < 4; j++) acc[i][j] = zero4;

  #pragma unroll
  for (int c = 0; c < 4; c++) {
    int row = c * 32 + arow0;
    size_t so = (size_t)row * 2048 + (size_t)(au ^ (row & 7)) * 16;
    gld16(abase + so, la[0] + c * 4096 + t * 16);
    gld16(bbase + so, lb[0] + c * 4096 + t * 16);
  }
  __syncthreads();

  for (int it = 0; it < 16; ++it) {
    int cur = it & 1;
    if (it < 15) {
      int k0 = (it + 1) * 64;
      #pragma unroll
      for (int c = 0; c < 4; c++) {
        int row = c * 32 + arow0;
        size_t so = (size_t)row * 2048 + (size_t)k0 * 2 +
                    (size_t)(au ^ (row & 7)) * 16;
        gld16(abase + so, la[cur ^ 1] + c * 4096 + t * 16);
        gld16(bbase + so, lb[cur ^ 1] + c * 4096 + t * 16);
      }
    }
    const char* lac = la[cur];
    const char* lbc = lb[cur];
    #pragma unroll
    for (int kh = 0; kh < 2; kh++) {
      s8v af[4], bfv[4];
      #pragma unroll
      for (int i = 0; i < 4; i++) {
        int r = wm + i * 16 + m;
        af[i] = *(const s8v*)(lac + r * 128 + (((kh * 4 + q) ^ (r & 7)) * 16));
      }
      #pragma unroll
      for (int j = 0; j < 4; j++) {
        int r = wn + j * 16 + m;
        bfv[j] = *(const s8v*)(lbc + r * 128 + (((kh * 4 + q) ^ (r & 7)) * 16));
      }
      #pragma unroll
      for (int i = 0; i < 4; i++)
        #pragma unroll
        for (int j = 0; j < 4; j++)
          acc[i][j] = __builtin_amdgcn_mfma_f32_16x16x32_bf16(af[i], bfv[j], acc[i][j], 0, 0, 0);
    }
    __syncthreads();
  }

  f2v tc[4];
  #pragma unroll
  for (int j = 0; j < 4; j++)
    tc[j] = *(const f2v*)(t12 + (size_t)(bn + wn + j * 16 + m) * 2);
  #pragma unroll
  for (int i = 0; i < 4; i++)
    #pragma unroll
    for (int r = 0; r < 4; r++) {
      int row = bm + wm + i * 16 + q * 4 + r;
      // reduce 16 per-head partials: lane m loads head m's (s,ss), butterfly
      f2v pp = *(const f2v*)(stp + ((size_t)row * 16 + m) * 2);
      float s_ = pp[0], ss_ = pp[1];
      #pragma unroll
      for (int mm = 1; mm < 16; mm <<= 1) {
        s_ += __shfl_xor(s_, mm, 64);
        ss_ += __shfl_xor(ss_, mm, 64);
      }
      float mean = s_ * (1.0f / 1024.0f);
      float rstd = rsqrtf(ss_ * (1.0f / 1024.0f) - mean * mean + 1e-5f);
      float mrs = -mean * rstd;
      #pragma unroll
      for (int j = 0; j < 4; j++) {
        int col = bn + wn + j * 16 + m;
        C[(size_t)row * 1024 + col] =
            rstd * acc[i][j][r] + mrs * tc[j][0] + tc[j][1];
      }
    }
}

extern "C" void kernel_launch(void* const* d_in, const int* in_sizes, int n_in,
                              void* d_out, int out_size, void* d_ws, size_t ws_size,
                              hipStream_t stream) {
  const float* xq  = (const float*)d_in[0];
  const float* xk  = (const float*)d_in[1];
  const float* xv  = (const float*)d_in[2];
  const float* qnw = (const float*)d_in[3];
  const float* qnb = (const float*)d_in[4];
  const float* knw = (const float*)d_in[5];
  const float* knb = (const float*)d_in[6];
  const float* nw  = (const float*)d_in[7];
  const float* nb  = (const float*)d_in[8];
  const float* pw  = (const float*)d_in[9];
  float* out = (float*)d_out;

  const size_t NEED = 22421504;  // aout + kws + vtp + W' + t12 + stp(1MB)
  if (ws_size >= NEED) {
    // fused path: final LN folded into proj epilogue; flash writes per-head
    // (s,ss) partials (no atomics); proj reduces 16 heads via lane-butterfly.
    short* aoutw = (short*)d_ws;
    short* kws = (short*)((char*)d_ws + 16777216);
    short* vtp = (short*)((char*)d_ws + 17956864);
    short* wpb = (short*)((char*)d_ws + 19267584);
    float* t12 = (float*)((char*)d_ws + 21364736);
    float* stp = (float*)((char*)d_ws + 21372928);
    prep_kernel<<<2176, 256, 0, stream>>>(xk, knw, knb, kws, xv, vtp,
                                          pw, nw, nb, wpb, t12);
    flash_kernel<<<1024, 256, 0, stream>>>(xq, qnw, qnb, kws, vtp, aoutw, stp);
    proj_gemm_fx<<<512, 256, 0, stream>>>(aoutw, wpb, t12, stp, out);
  } else {
    // fallback: r3 pipeline; stats partials land in dead back half of d_out
    short* kws = (short*)d_ws;
    short* vtp = (short*)((char*)d_ws + 0x120000);
    short* yws = (short*)d_ws;
    short* aout = (short*)d_out;
    float* stdummy = (float*)((char*)d_out + 20971520);
    prep_kernel<<<2112, 256, 0, stream>>>(xk, knw, knb, kws, xv, vtp,
                                          pw, nw, nb, (short*)d_ws, (float*)d_ws);
    flash_kernel<<<1024, 256, 0, stream>>>(xq, qnw, qnb, kws, vtp, aout, stdummy);
    ln_d_kernel<<<B_ * S_ / 4, 256, 0, stream>>>(aout, nw, nb, yws);
    proj_gemm_fb<<<512, 256, 0, stream>>>(yws, pw, out);
  }
}